// Round 13
// baseline (539.616 us; speedup 1.0000x reference)
//
#include <hip/hip_runtime.h>
#include <math.h>

#define YB (50*128*512)   // y_seq batch stride (floats)
#define YT (128*512)      // y_seq time stride
#define DTc 0.5f
#define NBLK 512

typedef __attribute__((ext_vector_type(8))) short bf16x8;
typedef __attribute__((ext_vector_type(4))) float f32x4;

__device__ __forceinline__ unsigned short f2bf(float f) {
    unsigned int u = __builtin_bit_cast(unsigned int, f);
    u += 0x7fffu + ((u >> 16) & 1u);          // RNE
    return (unsigned short)(u >> 16);
}
__device__ __forceinline__ float bf2f(unsigned short h) {
    unsigned int u = ((unsigned int)h) << 16;
    return __builtin_bit_cast(float, u);
}

__device__ __forceinline__ float tanh_fast(float x) {
    float ax = fabsf(x);
    float e  = __expf(-2.f * ax);
    float r  = (1.f - e) * __builtin_amdgcn_rcpf(1.f + e);
    return __builtin_copysignf(r, x);
}

// raw block barrier: waits LDS ops only, lets global stores stay in flight
__device__ __forceinline__ void lds_sync() {
    asm volatile("s_waitcnt lgkmcnt(0)" ::: "memory");
    __builtin_amdgcn_sched_barrier(0);
    __builtin_amdgcn_s_barrier();
    __builtin_amdgcn_sched_barrier(0);
}

// ==================== fused weight prep ====================
// wt floats: [0,9216) conv8 transposes.
// u16 region at wt+9216: 12 x 49152 kappa-format bf16 sets:
//   0 wy, 1 hw2, 2 hw3, 3 hw4, 4 ow2h,5 ow2l, 6 ow3h,7 ow3l, 8 aw2h,9 aw2l, 10 aw3h,11 aw3l
struct WSrc { const float* p[11]; };  // ow1,aw1,hw1, ow2,ow3,aw2,aw3,hw2,hw3,hw4, wy
__global__ void wprep_all_k(WSrc s, float* __restrict__ wt) {
    int idx = blockIdx.x * 256 + threadIdx.x;
    if (idx < 9216) {
        int wsel = idx / 3072, r = idx % 3072;
        int row = r >> 7, co = r & 127;
        int ci = row / 3, k = row - ci * 3;
        wt[idx] = s.p[wsel][(co * 8 + ci) * 3 + k];
    } else if (idx < 9216 + 589824) {
        int q = idx - 9216;
        int cv = q / 49152, r = q % 49152;
        int co = r / 384, kap = r % 384;
        int k = kap >> 7;
        int ci = ((kap >> 5) & 3) * 32 + (kap & 31);
        const int selmap[12] = {10, 7, 8, 9, 3, 3, 4, 4, 5, 5, 6, 6};
        float w = s.p[selmap[cv]][(co * 128 + ci) * 3 + k];
        unsigned short hv = f2bf(w);
        unsigned short ov = ((cv >= 4) && (cv & 1)) ? f2bf(w - bf2f(hv)) : hv;
        ((unsigned short*)(wt + 9216))[q] = ov;
    }
}

// ==================== conv8 layer (fp32, 3 jobs) ====================
struct Job { const float* src; float* dst; const float* wt; const float* bias; int sbs, dbs, act; };
struct Jobs3 { Job j[3]; };

__global__ __launch_bounds__(256) void conv8x3_k(Jobs3 js) {
    int jb = blockIdx.y % 3;
    Job jo = js.j[jb];
    int b = blockIdx.z, tile = blockIdx.x, tid = threadIdx.x;
    int l0 = tile * 64;
    int tl4 = (tid & 15) * 4;
    int co0 = (tid >> 4) * 8;
    __shared__ float xs[8 * 68];
    __shared__ float wsh[24 * 128];
    const float* sb = jo.src + (size_t)b * jo.sbs;
    for (int idx = tid; idx < 8 * 66; idx += 256) {
        int ci = idx / 66, ll = idx - ci * 66;
        int gl = l0 - 1 + ll;
        xs[ci * 68 + ll] = (gl >= 0 && gl < 512) ? sb[ci * 512 + gl] : 0.f;
    }
    for (int idx = tid; idx < 24 * 128; idx += 256) wsh[idx] = jo.wt[idx];
    __syncthreads();
    float acc[8][4] = {};
    #pragma unroll
    for (int ci = 0; ci < 8; ++ci) {
        float x6[6];
        #pragma unroll
        for (int j = 0; j < 6; ++j) x6[j] = xs[ci * 68 + tl4 + j];
        #pragma unroll
        for (int k = 0; k < 3; ++k) {
            float w8[8];
            #pragma unroll
            for (int i = 0; i < 8; ++i) w8[i] = wsh[(ci * 3 + k) * 128 + co0 + i];
            #pragma unroll
            for (int i = 0; i < 8; ++i)
                #pragma unroll
                for (int j = 0; j < 4; ++j)
                    acc[i][j] = fmaf(w8[i], x6[k + j], acc[i][j]);
        }
    }
    #pragma unroll
    for (int i = 0; i < 8; ++i) {
        int co = co0 + i;
        float bv = jo.bias[co];
        float4 o;
        o.x = fmaxf(acc[i][0] + bv, 0.f);
        o.y = fmaxf(acc[i][1] + bv, 0.f);
        o.z = fmaxf(acc[i][2] + bv, 0.f);
        o.w = fmaxf(acc[i][3] + bv, 0.f);
        *(float4*)(jo.dst + (size_t)b * jo.dbs + (size_t)co * 512 + l0 + tl4) = o;
    }
}

// ==================== unified MFMA conv128 (relu) ====================
// wlo != null: split-bf16 (xh*wh + xl*wh + xh*wl). wlo == null: plain bf16.
struct UJob { const float* src; float* dst; const unsigned short* whi;
              const unsigned short* wlo; const float* bias; int sbs, dbs; };
struct UJobs3 { UJob j[3]; };

__global__ __launch_bounds__(512) void uconv_k(UJobs3 js) {
    UJob jo = js.j[blockIdx.z];
    int tile = blockIdx.x, b = blockIdx.y;
    int tid = threadIdx.x, lane = tid & 63, wid = tid >> 6;
    int lr = lane & 15, kg = lane >> 4;
    int co = wid * 16 + lr;
    int l0 = tile * 32;
    bool dual = (jo.wlo != nullptr);

    __shared__ float stage[128 * 40];
    __shared__ uint4 hiX[34 * 16];
    __shared__ uint4 loX[34 * 16];

    const bf16x8* wph = (const bf16x8*)(jo.whi + (size_t)co * 384);
    bf16x8 Bh[12];
    #pragma unroll
    for (int s = 0; s < 12; ++s) Bh[s] = wph[s * 4 + kg];

    const float* sb = jo.src + (size_t)b * jo.sbs;
    for (int i = tid; i < 1280; i += 512) {
        int c = i / 10, p4 = (i - c * 10) * 4;
        int l = l0 - 4 + p4;
        f32x4 v;
        if (l >= 0 && l <= 508) {
            v = *(const f32x4*)(sb + (size_t)c * 512 + l);
        } else {
            #pragma unroll
            for (int e = 0; e < 4; ++e) {
                int le = l + e;
                v[e] = (le >= 0 && le < 512) ? sb[(size_t)c * 512 + le] : 0.f;
            }
        }
        *(f32x4*)(stage + c * 40 + p4) = v;
    }
    __syncthreads();
    for (int i = tid; i < 34 * 16; i += 512) {
        int h = i >> 4, c8 = i & 15;
        unsigned short ph[8], pl[8];
        #pragma unroll
        for (int q = 0; q < 8; ++q) {
            float x = stage[(c8 * 8 + q) * 40 + h + 3];
            unsigned short hv = f2bf(x);
            ph[q] = hv;
            pl[q] = f2bf(x - bf2f(hv));
        }
        int sx = h * 16 + (c8 ^ (h & 7));
        hiX[sx] = *(uint4*)ph;
        if (dual) loX[sx] = *(uint4*)pl;
    }
    __syncthreads();

    f32x4 acc[2];
    acc[0] = (f32x4){0.f, 0.f, 0.f, 0.f};
    acc[1] = (f32x4){0.f, 0.f, 0.f, 0.f};
    __builtin_amdgcn_s_setprio(1);
    if (dual) {
        const bf16x8* wpl = (const bf16x8*)(jo.wlo + (size_t)co * 384);
        bf16x8 blc = wpl[kg];
        #pragma unroll
        for (int s = 0; s < 12; ++s) {
            bf16x8 Bl = blc;
            if (s < 11) blc = wpl[(s + 1) * 4 + kg];
            int k = s >> 2;
            int chunk = (s & 3) * 4 + kg;
            #pragma unroll
            for (int lt = 0; lt < 2; ++lt) {
                int arow = 16 * lt + lr + k;
                int ai = arow * 16 + ((arow & 7) ^ chunk);
                bf16x8 ah = __builtin_bit_cast(bf16x8, hiX[ai]);
                bf16x8 al = __builtin_bit_cast(bf16x8, loX[ai]);
                acc[lt] = __builtin_amdgcn_mfma_f32_16x16x32_bf16(ah, Bh[s], acc[lt], 0, 0, 0);
                acc[lt] = __builtin_amdgcn_mfma_f32_16x16x32_bf16(al, Bh[s], acc[lt], 0, 0, 0);
                acc[lt] = __builtin_amdgcn_mfma_f32_16x16x32_bf16(ah, Bl,    acc[lt], 0, 0, 0);
            }
        }
    } else {
        #pragma unroll
        for (int s = 0; s < 12; ++s) {
            int k = s >> 2;
            int chunk = (s & 3) * 4 + kg;
            #pragma unroll
            for (int lt = 0; lt < 2; ++lt) {
                int arow = 16 * lt + lr + k;
                bf16x8 ah = __builtin_bit_cast(bf16x8, hiX[arow * 16 + ((arow & 7) ^ chunk)]);
                acc[lt] = __builtin_amdgcn_mfma_f32_16x16x32_bf16(ah, Bh[s], acc[lt], 0, 0, 0);
            }
        }
    }
    __builtin_amdgcn_s_setprio(0);

    float bv = jo.bias[co];
    #pragma unroll
    for (int lt = 0; lt < 2; ++lt) {
        float v[4];
        #pragma unroll
        for (int j = 0; j < 4; ++j) v[j] = fmaxf(acc[lt][j] + bv, 0.f);
        *(f32x4*)(jo.dst + (size_t)b * jo.dbs + (size_t)co * 512 + l0 + 16 * lt + 4 * kg) = *(f32x4*)v;
    }
}

// ==================== bf16-MFMA conv128 (hy4: tanh + HYT seed) ====================
__global__ __launch_bounds__(512) void mconv_k(
    const float* __restrict__ src, int sbs,
    float* __restrict__ dst, int dbs,
    const unsigned short* __restrict__ w2,
    const float* __restrict__ bias,
    unsigned short* __restrict__ hyt)
{
    int tile = blockIdx.x, b = blockIdx.y;
    int tid = threadIdx.x, lane = tid & 63, wid = tid >> 6;
    int lr = lane & 15, kg = lane >> 4;
    int co = wid * 16 + lr;
    int l0 = tile * 32;

    __shared__ float stage[128 * 40];
    __shared__ uint4 hyX[34 * 16];

    bf16x8 Bw[12];
    {
        const bf16x8* wp = (const bf16x8*)(w2 + (size_t)co * 384);
        #pragma unroll
        for (int s = 0; s < 12; ++s) Bw[s] = wp[s * 4 + kg];
    }

    const float* sb = src + (size_t)b * sbs;
    for (int i = tid; i < 1280; i += 512) {
        int c = i / 10, p4 = (i - c * 10) * 4;
        int l = l0 - 4 + p4;
        f32x4 v;
        if (l >= 0 && l <= 508) {
            v = *(const f32x4*)(sb + (size_t)c * 512 + l);
        } else {
            #pragma unroll
            for (int e = 0; e < 4; ++e) {
                int le = l + e;
                v[e] = (le >= 0 && le < 512) ? sb[(size_t)c * 512 + le] : 0.f;
            }
        }
        *(f32x4*)(stage + c * 40 + p4) = v;
    }
    __syncthreads();
    for (int i = tid; i < 34 * 16; i += 512) {
        int h = i >> 4, c8 = i & 15;
        unsigned short pk[8];
        #pragma unroll
        for (int q = 0; q < 8; ++q) pk[q] = f2bf(stage[(c8 * 8 + q) * 40 + h + 3]);
        hyX[h * 16 + (c8 ^ (h & 7))] = *(uint4*)pk;
    }
    __syncthreads();

    f32x4 acc[2];
    acc[0] = (f32x4){0.f, 0.f, 0.f, 0.f};
    acc[1] = (f32x4){0.f, 0.f, 0.f, 0.f};
    __builtin_amdgcn_s_setprio(1);
    #pragma unroll
    for (int s = 0; s < 12; ++s) {
        int k = s >> 2;
        int chunk = (s & 3) * 4 + kg;
        bf16x8 Bf = Bw[s];
        #pragma unroll
        for (int lt = 0; lt < 2; ++lt) {
            int arow = 16 * lt + lr + k;
            bf16x8 a = __builtin_bit_cast(bf16x8, hyX[arow * 16 + ((arow & 7) ^ chunk)]);
            acc[lt] = __builtin_amdgcn_mfma_f32_16x16x32_bf16(a, Bf, acc[lt], 0, 0, 0);
        }
    }
    __builtin_amdgcn_s_setprio(0);

    float bv = bias[co];
    float vv[2][4];
    #pragma unroll
    for (int lt = 0; lt < 2; ++lt) {
        #pragma unroll
        for (int j = 0; j < 4; ++j)
            vv[lt][j] = tanh_fast(acc[lt][j] + bv);
        *(f32x4*)(dst + (size_t)b * dbs + (size_t)co * 512 + l0 + 16 * lt + 4 * kg) = *(f32x4*)vv[lt];
    }

    lds_sync();                       // all hyX MFMA reads complete
    {
        unsigned short* t16 = (unsigned short*)hyX;
        #pragma unroll
        for (int lt = 0; lt < 2; ++lt)
            #pragma unroll
            for (int j = 0; j < 4; ++j)
                t16[(16 * lt + 4 * kg + j) * 128 + co] = f2bf(vv[lt][j]);
        lds_sync();
        int row = tid >> 4, c8 = tid & 15;    // tid < 512 -> row < 32
        ((uint4*)hyt)[((size_t)b * 512 + l0 + row) * 16 + c8] =
            ((uint4*)hyX)[row * 16 + c8];
    }
}

// ==================== grid barrier ====================
__global__ void zero_bar_k(unsigned* bar) { if (threadIdx.x < 2) bar[threadIdx.x] = 0u; }

__device__ __forceinline__ void grid_barrier(unsigned* bar) {
    unsigned g = __hip_atomic_load(bar + 1, __ATOMIC_ACQUIRE, __HIP_MEMORY_SCOPE_AGENT);
    unsigned a = __hip_atomic_fetch_add(bar, 1u, __ATOMIC_ACQ_REL, __HIP_MEMORY_SCOPE_AGENT);
    if (a == NBLK - 1) {
        __hip_atomic_store(bar, 0u, __ATOMIC_RELAXED, __HIP_MEMORY_SCOPE_AGENT);
        __hip_atomic_fetch_add(bar + 1, 1u, __ATOMIC_ACQ_REL, __HIP_MEMORY_SCOPE_AGENT);
    } else {
        while (__hip_atomic_load(bar + 1, __ATOMIC_ACQUIRE, __HIP_MEMORY_SCOPE_AGENT) == g)
            __builtin_amdgcn_s_sleep(8);
    }
}

// ==================== ns-step chunk kernel (fallback path) ====================
__global__ __launch_bounds__(512, 2) void chunk_k(
    const unsigned short* __restrict__ hyt_in,   // [b][512][16] uint4 bf16
    unsigned short* __restrict__ hyt_out,
    const float* __restrict__ hy_in,   // fp32 [b][co][l], b-stride YB
    const float* __restrict__ hz_in,   // [b][co][l], b-stride 65536
    float* __restrict__ hz_out,
    const float* __restrict__ omega, const float* __restrict__ alpha,
    const unsigned short* __restrict__ w2,
    float* __restrict__ ybase,         // slab t0 base
    float* __restrict__ part, int t0, int ns)
{
    int tile = blockIdx.x, b = blockIdx.y;
    int tid = threadIdx.x, lane = tid & 63, wid = tid >> 6;
    int lr = lane & 15, kg = lane >> 4;
    int co = wid * 16 + lr;
    int l0 = tile * 32;

    __shared__ uint4 hySd[2][800];         // [buf][row h 0..49][chunk ^ (h&7)]
    __shared__ float ytmp[2 * 4608];       // [buf][co][36]

    bf16x8 Bw[12];
    {
        const bf16x8* wp = (const bf16x8*)(w2 + (size_t)co * 384);
        #pragma unroll
        for (int s = 0; s < 12; ++s) Bw[s] = wp[s * 4 + kg];
    }

    f32x4 hyR[3], hzR[3], omR[3], alR[3];

    // ---- prologue
    {
        const uint4* hsrc = (const uint4*)hyt_in + (size_t)b * 8192;
        for (int i = tid; i < 800; i += 512) {
            int h = i >> 4, c8 = i & 15;
            int l = (l0 - 9 + h) & 511;
            hySd[0][h * 16 + (c8 ^ (h & 7))] = hsrc[l * 16 + c8];
        }
    }
    {
        const float* src = hy_in + (size_t)b * YB;
        size_t ob = (size_t)b * 65536 + (size_t)co * 512;
        #pragma unroll
        for (int lt = 0; lt < 3; ++lt) {
            int l = (l0 - 8 + 16 * lt + 4 * kg) & 511;
            hyR[lt] = *(const f32x4*)(src + (size_t)co * 512 + l);
            omR[lt] = *(const f32x4*)(omega + ob + l);
            alR[lt] = *(const f32x4*)(alpha + ob + l);
            if (t0 > 0) hzR[lt] = *(const f32x4*)(hz_in + ob + l);
            else        hzR[lt] = (f32x4){0.f, 0.f, 0.f, 0.f};
        }
    }
    __syncthreads();

    for (int i = 0; i < ns; ++i) {
        const uint4* hc = &hySd[i & 1][0];
        unsigned short* hn16 = (unsigned short*)&hySd[(i + 1) & 1][0];
        float* yt = ytmp + (i & 1) * 4608;

        f32x4 acc[3];
        #pragma unroll
        for (int lt = 0; lt < 3; ++lt) acc[lt] = (f32x4){0.f, 0.f, 0.f, 0.f};
        __builtin_amdgcn_s_setprio(1);
        #pragma unroll
        for (int s = 0; s < 12; ++s) {
            int chunk = (s & 3) * 4 + kg;
            int k = s >> 2;
            bf16x8 Bf = Bw[s];
            #pragma unroll
            for (int lt = 0; lt < 3; ++lt) {
                int arow = 16 * lt + lr + k;
                bf16x8 a = __builtin_bit_cast(bf16x8, hc[arow * 16 + ((arow & 7) ^ chunk)]);
                acc[lt] = __builtin_amdgcn_mfma_f32_16x16x32_bf16(a, Bf, acc[lt], 0, 0, 0);
            }
        }
        __builtin_amdgcn_s_setprio(0);

        float lsum = 0.f;
        #pragma unroll
        for (int lt = 0; lt < 3; ++lt) {
            #pragma unroll
            for (int j = 0; j < 4; ++j) {
                float spring = tanh_fast(acc[lt][j]);
                float zn = hzR[lt][j] + DTc * (spring - omR[lt][j] * hyR[lt][j] - alR[lt][j] * hzR[lt][j]);
                float hn = hyR[lt][j] + DTc * zn;
                hzR[lt][j] = zn;
                hyR[lt][j] = hn;
            }
            bool valid = (lt == 0) ? (kg >= 2) : (lt == 2) ? (kg < 2) : true;
            int r0 = 16 * lt + 4 * kg;
            if (valid) {
                *(f32x4*)(yt + co * 36 + (r0 - 8)) = hyR[lt];
                lsum += hyR[lt][0] + hyR[lt][1] + hyR[lt][2] + hyR[lt][3];
                if (i == ns - 1)
                    *(f32x4*)(hz_out + (size_t)b * 65536 + (size_t)co * 512 + l0 + (r0 - 8)) = hzR[lt];
            }
            #pragma unroll
            for (int j = 0; j < 4; ++j) {
                int rr = r0 + j + 1;
                int sidx = rr * 128 + (((co >> 3) ^ (rr & 7)) << 3) + (co & 7);
                hn16[sidx] = f2bf(hyR[lt][j]);
            }
        }
        lsum += __shfl_xor(lsum, 16);
        lsum += __shfl_xor(lsum, 32);
        if (kg == 0) part[(((size_t)b * 50 + t0 + i) * 128 + co) * 16 + tile] = lsum;

        lds_sync();

        {
            float* yrow = ybase + (size_t)b * YB + (size_t)i * YT;
            int cs2 = wid * 16 + (lane >> 3);
            int lq = (lane & 7) * 4;
            #pragma unroll
            for (int cq = 0; cq < 2; ++cq) {
                int c2 = cs2 + cq * 8;
                f32x4 v = *(const f32x4*)(yt + c2 * 36 + lq);
                *(f32x4*)(yrow + (size_t)c2 * 512 + l0 + lq) = v;
            }
        }
    }

    {
        const uint4* hl = &hySd[ns & 1][0];
        int row = tid >> 4, c8 = tid & 15;
        int h = row + 9;
        ((uint4*)hyt_out)[((size_t)b * 512 + l0 + row) * 16 + c8] =
            hl[h * 16 + (c8 ^ (h & 7))];
    }
}

// ==================== persistent recurrence (primary path) ====================
// All 50 steps in one launch; boundary exchange every 8 steps via y slab + HZE
// parity buffer + 512-wide grid barrier (r4-validated algebra). Requires 2
// blocks/CU co-residency — gated host-side by occupancy query.
__global__ __launch_bounds__(512, 2) void recur_p_k(
    const unsigned short* __restrict__ hyt_in,   // HYT0 seed
    const float* __restrict__ hy_in,             // HY0 fp32
    const float* __restrict__ omega, const float* __restrict__ alpha,
    const unsigned short* __restrict__ w2,
    float* __restrict__ yout,                    // slab 0 base
    float* __restrict__ hze,                     // [2][32][16][128][16] f32
    float* __restrict__ part,
    unsigned* __restrict__ bar)
{
    int tile = blockIdx.x, b = blockIdx.y;
    int tid = threadIdx.x, lane = tid & 63, wid = tid >> 6;
    int lr = lane & 15, kg = lane >> 4;
    int co = wid * 16 + lr;
    int l0 = tile * 32;

    __shared__ uint4 hySd[2][800];
    __shared__ float ytmp[2 * 4608];

    bf16x8 Bw[12];
    {
        const bf16x8* wp = (const bf16x8*)(w2 + (size_t)co * 384);
        #pragma unroll
        for (int s = 0; s < 12; ++s) Bw[s] = wp[s * 4 + kg];
    }

    f32x4 hyR[3], hzR[3], omR[3], alR[3];

    // ---- prologue (t=0)
    {
        const uint4* hsrc = (const uint4*)hyt_in + (size_t)b * 8192;
        for (int i = tid; i < 800; i += 512) {
            int h = i >> 4, c8 = i & 15;
            int l = (l0 - 9 + h) & 511;
            hySd[0][h * 16 + (c8 ^ (h & 7))] = hsrc[l * 16 + c8];
        }
    }
    {
        const float* src = hy_in + (size_t)b * YB;
        size_t ob = (size_t)b * 65536 + (size_t)co * 512;
        #pragma unroll
        for (int lt = 0; lt < 3; ++lt) {
            int l = (l0 - 8 + 16 * lt + 4 * kg) & 511;
            hyR[lt] = *(const f32x4*)(src + (size_t)co * 512 + l);
            omR[lt] = *(const f32x4*)(omega + ob + l);
            alR[lt] = *(const f32x4*)(alpha + ob + l);
            hzR[lt] = (f32x4){0.f, 0.f, 0.f, 0.f};
        }
    }
    __syncthreads();

    for (int t = 0; t < 50; ++t) {
        const uint4* hc = &hySd[t & 1][0];
        unsigned short* hn16 = (unsigned short*)&hySd[(t + 1) & 1][0];
        float* yt = ytmp + (t & 1) * 4608;

        f32x4 acc[3];
        #pragma unroll
        for (int lt = 0; lt < 3; ++lt) acc[lt] = (f32x4){0.f, 0.f, 0.f, 0.f};
        __builtin_amdgcn_s_setprio(1);
        #pragma unroll
        for (int s = 0; s < 12; ++s) {
            int chunk = (s & 3) * 4 + kg;
            int k = s >> 2;
            bf16x8 Bf = Bw[s];
            #pragma unroll
            for (int lt = 0; lt < 3; ++lt) {
                int arow = 16 * lt + lr + k;
                bf16x8 a = __builtin_bit_cast(bf16x8, hc[arow * 16 + ((arow & 7) ^ chunk)]);
                acc[lt] = __builtin_amdgcn_mfma_f32_16x16x32_bf16(a, Bf, acc[lt], 0, 0, 0);
            }
        }
        __builtin_amdgcn_s_setprio(0);

        float lsum = 0.f;
        #pragma unroll
        for (int lt = 0; lt < 3; ++lt) {
            #pragma unroll
            for (int j = 0; j < 4; ++j) {
                float spring = tanh_fast(acc[lt][j]);
                float zn = hzR[lt][j] + DTc * (spring - omR[lt][j] * hyR[lt][j] - alR[lt][j] * hzR[lt][j]);
                float hn = hyR[lt][j] + DTc * zn;
                hzR[lt][j] = zn;
                hyR[lt][j] = hn;
            }
            bool valid = (lt == 0) ? (kg >= 2) : (lt == 2) ? (kg < 2) : true;
            int r0 = 16 * lt + 4 * kg;
            if (valid) {
                *(f32x4*)(yt + co * 36 + (r0 - 8)) = hyR[lt];
                lsum += hyR[lt][0] + hyR[lt][1] + hyR[lt][2] + hyR[lt][3];
            }
            #pragma unroll
            for (int j = 0; j < 4; ++j) {
                int rr = r0 + j + 1;
                int sidx = rr * 128 + (((co >> 3) ^ (rr & 7)) << 3) + (co & 7);
                hn16[sidx] = f2bf(hyR[lt][j]);
            }
        }
        lsum += __shfl_xor(lsum, 16);
        lsum += __shfl_xor(lsum, 32);
        if (kg == 0) part[(((size_t)b * 50 + t) * 128 + co) * 16 + tile] = lsum;

        lds_sync();

        // coalesced y store
        {
            float* yrow = yout + (size_t)b * YB + (size_t)t * YT;
            int cs2 = wid * 16 + (lane >> 3);
            int lq = (lane & 7) * 4;
            #pragma unroll
            for (int cq = 0; cq < 2; ++cq) {
                int c2 = cs2 + cq * 8;
                f32x4 v = *(const f32x4*)(yt + c2 * 36 + lq);
                *(f32x4*)(yrow + (size_t)c2 * 512 + l0 + lq) = v;
            }
        }

        if ((t & 7) == 7 && t < 49) {
            // ---- boundary: hz edge export, grid barrier, halo refresh
            int par = (t >> 3) & 1;
            float* hb = hze + ((((size_t)par * 32 + b) * 16 + tile) * 128 + co) * 16;
            if (kg >= 2) *(f32x4*)(hb + (kg - 2) * 4) = hzR[0];   // rows 8..15
            else         *(f32x4*)(hb + 8 + kg * 4)  = hzR[2];   // rows 32..39
            __threadfence();
            __syncthreads();
            if (tid == 0) grid_barrier(bar);
            __syncthreads();
            __threadfence();
            const float* ycur = yout + (size_t)b * YB + (size_t)t * YT;
            if (kg < 2) {    // refresh state rows 0..7
                hyR[0] = *(const f32x4*)(ycur + (size_t)co * 512 + ((l0 - 8 + kg * 4) & 511));
                const float* hbl = hze + ((((size_t)par * 32 + b) * 16 + ((tile + 15) & 15)) * 128 + co) * 16;
                hzR[0] = *(const f32x4*)(hbl + 8 + kg * 4);
            } else {         // refresh state rows 40..47
                hyR[2] = *(const f32x4*)(ycur + (size_t)co * 512 + ((l0 + 24 + kg * 4) & 511));
                const float* hbr = hze + ((((size_t)par * 32 + b) * 16 + ((tile + 1) & 15)) * 128 + co) * 16;
                hzR[2] = *(const f32x4*)(hbr + (kg - 2) * 4);
            }
            // refresh hyS halo rows 0..8, 41..49 of next buffer
            for (int i2 = tid; i2 < 18 * 128; i2 += 512) {
                int hr = i2 >> 7, c = i2 & 127;
                int h = (hr < 9) ? hr : (32 + hr);
                int l = (l0 - 9 + h) & 511;
                float v = ycur[(size_t)c * 512 + l];
                int sidx = h * 128 + (((c >> 3) ^ (h & 7)) << 3) + (c & 7);
                hn16[sidx] = f2bf(v);
            }
            __syncthreads();
        }
    }
}

// ==================== readout ====================
__global__ __launch_bounds__(256) void readout_k(
    const float* __restrict__ part, const float* __restrict__ fct,
    const float* __restrict__ rw1, const float* __restrict__ rb1,
    const float* __restrict__ rw2, const float* __restrict__ rb2,
    const float* __restrict__ rw3, const float* __restrict__ rb3,
    float* __restrict__ out)
{
    int b = blockIdx.x, tid = threadIdx.x;
    __shared__ float ybar[50 * 128];
    __shared__ float feat[26 * 128];
    __shared__ float h1[64];
    __shared__ float h2[32];
    for (int idx = tid; idx < 50 * 128; idx += 256) {
        const float* p = part + ((size_t)b * 6400 + idx) * 16;
        float s = 0.f;
        #pragma unroll
        for (int q = 0; q < 16; ++q) s += p[q];
        ybar[idx] = s * (1.f / 512.f);
    }
    __syncthreads();
    for (int idx = tid; idx < 26 * 128; idx += 256) {
        int k = idx >> 7, c = idx & 127;
        float s = 0.f;
        for (int t = 0; t < 50; ++t) s += fct[k * 50 + t] * ybar[t * 128 + c];
        feat[idx] = s;
    }
    __syncthreads();
    {
        int j = tid >> 2, q = tid & 3;
        float s = 0.f;
        const float* r = rw1 + (size_t)j * 3328 + q * 832;
        const float* f = feat + q * 832;
        for (int i = 0; i < 832; ++i) s += f[i] * r[i];
        s += __shfl_xor(s, 1);
        s += __shfl_xor(s, 2);
        if (q == 0) h1[j] = fmaxf(s + rb1[j], 0.f);
    }
    __syncthreads();
    if (tid < 32) {
        float s = 0.f;
        for (int i = 0; i < 64; ++i) s += h1[i] * rw2[tid * 64 + i];
        h2[tid] = fmaxf(s + rb2[tid], 0.f);
    }
    __syncthreads();
    if (tid == 0) {
        float s = 0.f;
        for (int i = 0; i < 32; ++i) s += h2[i] * rw3[i];
        out[b] = s + rb3[0];
    }
}

// ==================== launch ====================
extern "C" void kernel_launch(void* const* d_in, const int* in_sizes, int n_in,
                              void* d_out, int out_size, void* d_ws, size_t ws_size,
                              hipStream_t stream)
{
    const float* x   = (const float*)d_in[0];
    const float* ow1 = (const float*)d_in[1];  const float* ob1 = (const float*)d_in[2];
    const float* ow2 = (const float*)d_in[3];  const float* ob2 = (const float*)d_in[4];
    const float* ow3 = (const float*)d_in[5];  const float* ob3 = (const float*)d_in[6];
    const float* aw1 = (const float*)d_in[7];  const float* ab1 = (const float*)d_in[8];
    const float* aw2 = (const float*)d_in[9];  const float* ab2 = (const float*)d_in[10];
    const float* aw3 = (const float*)d_in[11]; const float* ab3 = (const float*)d_in[12];
    const float* hw1 = (const float*)d_in[13]; const float* hb1 = (const float*)d_in[14];
    const float* hw2 = (const float*)d_in[15]; const float* hb2 = (const float*)d_in[16];
    const float* hw3 = (const float*)d_in[17]; const float* hb3 = (const float*)d_in[18];
    const float* hw4 = (const float*)d_in[19]; const float* hb4 = (const float*)d_in[20];
    const float* wy  = (const float*)d_in[21];
    const float* fct = (const float*)d_in[22];
    const float* rw1 = (const float*)d_in[23]; const float* rb1 = (const float*)d_in[24];
    const float* rw2 = (const float*)d_in[25]; const float* rb2 = (const float*)d_in[26];
    const float* rw3 = (const float*)d_in[27]; const float* rb3 = (const float*)d_in[28];

    float* out  = (float*)d_out;
    float* yout = out + 32;                       // y_seq region
    float* ws   = (float*)d_ws;

    // ws layout (float offsets)
    float* OMEGA = ws;                            // 2,097,152
    float* ALPHA = ws + 2097152;                  // 2,097,152
    float* WT    = ws + 4194304;                  // 304,128
    float* PART  = ws + 4498432;                  // 3,276,800
    float* HZ0   = ws + 7775232;                  // 2,097,152 (persistent path: HZE)
    float* HZ1   = ws + 9872384;                  // 2,097,152 (fallback only)
    unsigned short* HYT0 = (unsigned short*)(ws + 11969536);   // 4MB
    unsigned short* HYT1 = (unsigned short*)(ws + 13018112);   // 4MB (fallback only)
    unsigned* BAR = (unsigned*)(ws + 14066688);   // 2 u32; end ~56.3MB
    float* HZE = HZ0;

    // encoder scratch slabs inside y region (overwritten at t >= 42, after last use)
    float* To1 = yout + 44 * YT;
    float* Ta1 = yout + 45 * YT;
    float* Th1 = yout + 46 * YT;
    float* To2 = yout + 47 * YT;
    float* Ta2 = yout + 43 * YT;
    float* Th2 = yout + 49 * YT;
    float* Th3 = yout + 42 * YT;
    float* HY0 = yout + 48 * YT;

    float* OW1T = WT + 0;  float* AW1T = WT + 3072;  float* HW1T = WT + 6144;
    unsigned short* U16 = (unsigned short*)(WT + 9216);
    unsigned short* W2WY = U16;
    unsigned short* W2H2 = U16 + 49152;
    unsigned short* W2H3 = U16 + 98304;
    unsigned short* W2H4 = U16 + 147456;
    unsigned short* OW2H = U16 + 196608;  unsigned short* OW2L = U16 + 245760;
    unsigned short* OW3H = U16 + 294912;  unsigned short* OW3L = U16 + 344064;
    unsigned short* AW2H = U16 + 393216;  unsigned short* AW2L = U16 + 442368;
    unsigned short* AW3H = U16 + 491520;  unsigned short* AW3L = U16 + 540672;

    WSrc wsrc;
    wsrc.p[0] = ow1; wsrc.p[1] = aw1; wsrc.p[2] = hw1;
    wsrc.p[3] = ow2; wsrc.p[4] = ow3; wsrc.p[5] = aw2; wsrc.p[6] = aw3;
    wsrc.p[7] = hw2; wsrc.p[8] = hw3; wsrc.p[9] = hw4; wsrc.p[10] = wy;
    wprep_all_k<<<2340, 256, 0, stream>>>(wsrc, WT);

    Jobs3 d1 = {{ {x, To1, OW1T, ob1, 4096, YB, 1},
                  {x, Ta1, AW1T, ab1, 4096, YB, 1},
                  {x, Th1, HW1T, hb1, 4096, YB, 1} }};
    conv8x3_k<<<dim3(8, 3, 32), 256, 0, stream>>>(d1);

    UJobs3 u2 = {{ {To1, To2, OW2H, OW2L, ob2, YB, YB},
                   {Ta1, Ta2, AW2H, AW2L, ab2, YB, YB},
                   {Th1, Th2, W2H2, nullptr, hb2, YB, YB} }};
    uconv_k<<<dim3(16, 32, 3), 512, 0, stream>>>(u2);

    UJobs3 u3 = {{ {To2, OMEGA, OW3H, OW3L, ob3, YB, 65536},
                   {Ta2, ALPHA, AW3H, AW3L, ab3, YB, 65536},
                   {Th2, Th3, W2H3, nullptr, hb3, YB, YB} }};
    uconv_k<<<dim3(16, 32, 3), 512, 0, stream>>>(u3);

    mconv_k<<<dim3(16, 32), 512, 0, stream>>>(Th3, YB, HY0, YB, W2H4, hb4, HYT0);

    // ---- recurrence: persistent if 2 blocks/CU fit (deadlock-proof gate),
    // else proven chunked path.
    int nb = 0;
    hipOccupancyMaxActiveBlocksPerMultiprocessor(&nb, recur_p_k, 512, 0);
    if (nb >= 2) {
        zero_bar_k<<<1, 64, 0, stream>>>(BAR);
        recur_p_k<<<dim3(16, 32), 512, 0, stream>>>(HYT0, HY0, OMEGA, ALPHA, W2WY,
                                                    yout, HZE, PART, BAR);
    } else {
        int t0 = 0, c = 0;
        while (t0 < 50) {
            int ns = (50 - t0 >= 8) ? 8 : (50 - t0);
            const unsigned short* hin = (c & 1) ? HYT1 : HYT0;
            unsigned short* hout      = (c & 1) ? HYT0 : HYT1;
            const float* hyin = (t0 == 0) ? HY0 : (yout + (size_t)(t0 - 1) * YT);
            const float* hzin = (c & 1) ? HZ1 : HZ0;
            float* hzout      = (c & 1) ? HZ0 : HZ1;
            chunk_k<<<dim3(16, 32), 512, 0, stream>>>(hin, hout, hyin, hzin, hzout,
                                                      OMEGA, ALPHA, W2WY,
                                                      yout + (size_t)t0 * YT, PART, t0, ns);
            t0 += ns; ++c;
        }
    }

    readout_k<<<32, 256, 0, stream>>>(PART, fct, rw1, rb1, rw2, rb2, rw3, rb3, out);
}